// Round 1
// baseline (343.053 us; speedup 1.0000x reference)
//
#include <hip/hip_runtime.h>
#include <hip/hip_bf16.h>
#include <math.h>

typedef __bf16 bf16x8 __attribute__((ext_vector_type(8)));
typedef float  f32x4  __attribute__((ext_vector_type(4)));

#define NTOK   32768
#define DDIM   512
#define KCOD   2048

#define Q_OFF    1
#define PERP_OFF 16777217
#define ENC_OFF  16777218

// ws layout (bytes)
#define WS_EBF   0           // 2048*512*2  = 2,097,152   bf16 E
#define WS_SE    2097152     // 2048*4      = 8,192       ||e||^2
#define WS_WVAL  2105344     // 32768*32*4  = 4,194,304   per-colgroup min val
#define WS_WIDX  6299648     // 32768*32*4  = 4,194,304   per-colgroup min idx
#define WS_IDX   10493952    // 32768*4     = 131,072     final argmin
#define WS_CNT   10625024    // 2048*4      = 8,192       histogram
#define WS_LOSS  10633216    // 32768*4     = 131,072     per-row loss partials

// ---------------- prep: E f32 -> bf16, se[k] = ||e_k||^2, zero counts -------
__global__ __launch_bounds__(64) void vq_prep(const float* __restrict__ E,
                                              __bf16* __restrict__ Ebf,
                                              float* __restrict__ se,
                                              int* __restrict__ counts) {
  int b = blockIdx.x, lane = threadIdx.x;
  const float4* src = (const float4*)(E + (size_t)b * DDIM) + lane * 2;
  float4 v0 = src[0], v1 = src[1];
  bf16x8 pk;
  pk[0] = (__bf16)v0.x; pk[1] = (__bf16)v0.y; pk[2] = (__bf16)v0.z; pk[3] = (__bf16)v0.w;
  pk[4] = (__bf16)v1.x; pk[5] = (__bf16)v1.y; pk[6] = (__bf16)v1.z; pk[7] = (__bf16)v1.w;
  *(bf16x8*)(Ebf + (size_t)b * DDIM + lane * 8) = pk;
  float ss = v0.x*v0.x + v0.y*v0.y + v0.z*v0.z + v0.w*v0.w
           + v1.x*v1.x + v1.y*v1.y + v1.z*v1.z + v1.w*v1.w;
  #pragma unroll
  for (int d = 1; d < 64; d <<= 1) ss += __shfl_xor(ss, d);
  if (lane == 0) se[b] = ss;
  if (b < KCOD / 64) counts[b * 64 + lane] = 0;
}

// ---------------- distance GEMM + per-block argmin --------------------------
// C[row][code] = dot(x_row, e_code); dist = se[code] - 2*C. 128x128 tile,
// BK=64, 4 waves (2x2), 16x16x32 bf16 MFMA. B via global_load_lds (bf16),
// A reg-staged with fused f32->bf16 convert.
__global__ __launch_bounds__(256) void vq_gemm(const float* __restrict__ X,
                                               const __bf16* __restrict__ Ebf,
                                               const float* __restrict__ se,
                                               float* __restrict__ wval,
                                               int* __restrict__ widx) {
  __shared__ __bf16 sA[128][64];
  __shared__ __bf16 sB[128][64];
  const int t = threadIdx.x;
  const int lane = t & 63, wid = t >> 6;
  const int wr = wid >> 1, wc = wid & 1;
  const int lr = lane & 15, lg = lane >> 4;
  const int brow = blockIdx.x * 128;
  const int bcol = blockIdx.y * 128;

  f32x4 zero = {0.f, 0.f, 0.f, 0.f};
  f32x4 acc[4][4];
  #pragma unroll
  for (int m = 0; m < 4; ++m)
    #pragma unroll
    for (int n = 0; n < 4; ++n) acc[m][n] = zero;

  const int ar = t >> 1, ah = t & 1;  // A staging: row 0..127, 32-col half
  const float* aG = X + (size_t)(brow + ar) * DDIM + ah * 32;
  __bf16* aL = &sA[ar][ah * 32];

  for (int kt = 0; kt < DDIM / 64; ++kt) {
    // B tile: 128 codes x 64 k, bf16, 16KB; 4 x 16B per thread, linear dest
    #pragma unroll
    for (int i = 0; i < 4; ++i) {
      int o = i * 4096 + t * 16;     // byte offset in sB
      int row = o >> 7;              // 128B per row
      int cb  = o & 127;
      const char* src = (const char*)Ebf +
          ((size_t)(bcol + row) * DDIM + kt * 64) * 2 + cb;
      __builtin_amdgcn_global_load_lds(
          (__attribute__((address_space(1))) void*)src,
          (__attribute__((address_space(3))) void*)((char*)&sB[0][0] + o),
          16, 0, 0);
    }
    // A tile: 128 rows x 64 k f32 -> bf16
    const float4* g4 = (const float4*)(aG + kt * 64);
    #pragma unroll
    for (int j = 0; j < 4; ++j) {
      float4 v0 = g4[2 * j], v1 = g4[2 * j + 1];
      bf16x8 pk;
      pk[0] = (__bf16)v0.x; pk[1] = (__bf16)v0.y; pk[2] = (__bf16)v0.z; pk[3] = (__bf16)v0.w;
      pk[4] = (__bf16)v1.x; pk[5] = (__bf16)v1.y; pk[6] = (__bf16)v1.z; pk[7] = (__bf16)v1.w;
      *(bf16x8*)(aL + 8 * j) = pk;
    }
    __syncthreads();
    #pragma unroll
    for (int kk = 0; kk < 2; ++kk) {
      bf16x8 a[4], b[4];
      #pragma unroll
      for (int m = 0; m < 4; ++m)
        a[m] = *(const bf16x8*)&sA[wr * 64 + m * 16 + lr][kk * 32 + lg * 8];
      #pragma unroll
      for (int n = 0; n < 4; ++n)
        b[n] = *(const bf16x8*)&sB[wc * 64 + n * 16 + lr][kk * 32 + lg * 8];
      #pragma unroll
      for (int m = 0; m < 4; ++m)
        #pragma unroll
        for (int n = 0; n < 4; ++n)
          acc[m][n] = __builtin_amdgcn_mfma_f32_16x16x32_bf16(a[m], b[n], acc[m][n], 0, 0, 0);
    }
    __syncthreads();
  }

  // epilogue: dist = se - 2*acc; argmin over this wave's 64 codes.
  // C/D layout: col = lane&15, row = (lane>>4)*4 + reg  [m89-verified]
  float sev[4]; int coln[4];
  #pragma unroll
  for (int n = 0; n < 4; ++n) {
    coln[n] = bcol + wc * 64 + n * 16 + lr;
    sev[n] = se[coln[n]];
  }
  const int g = blockIdx.y * 2 + wc;  // col-group 0..31
  #pragma unroll
  for (int m = 0; m < 4; ++m) {
    #pragma unroll
    for (int r = 0; r < 4; ++r) {
      float best = 1e30f; int bi = 0x7fffffff;
      #pragma unroll
      for (int n = 0; n < 4; ++n) {
        float v = sev[n] - 2.0f * acc[m][n][r];
        if (v < best || (v == best && coln[n] < bi)) { best = v; bi = coln[n]; }
      }
      #pragma unroll
      for (int d = 1; d < 16; d <<= 1) {  // reduce across the 16 col-lanes
        float ov = __shfl_xor(best, d);
        int   oi = __shfl_xor(bi, d);
        if (ov < best || (ov == best && oi < bi)) { best = ov; bi = oi; }
      }
      if (lr == 0) {
        int grow = brow + wr * 64 + m * 16 + lg * 4 + r;
        wval[(size_t)grow * 32 + g] = best;
        widx[(size_t)grow * 32 + g] = bi;
      }
    }
  }
}

// ---------------- argmin cross-group reduce (32 groups per row) -------------
__global__ __launch_bounds__(256) void vq_reduce(const float* __restrict__ wval,
                                                 const int* __restrict__ widx,
                                                 int* __restrict__ idxO) {
  int row = blockIdx.x * 4 + (threadIdx.x >> 6);
  int lane = threadIdx.x & 63;
  float v = 1e30f; int i = 0x7fffffff;
  if (lane < 32) {
    v = wval[(size_t)row * 32 + lane];
    i = widx[(size_t)row * 32 + lane];
  }
  #pragma unroll
  for (int d = 1; d < 64; d <<= 1) {
    float ov = __shfl_xor(v, d); int oi = __shfl_xor(i, d);
    if (ov < v || (ov == v && oi < i)) { v = ov; i = oi; }
  }
  if (lane == 0) idxO[row] = i;
}

// ---------------- gather quantized + loss partial + histogram ---------------
__global__ __launch_bounds__(128) void vq_gather(const float* __restrict__ X,
                                                 const float* __restrict__ E,
                                                 const int* __restrict__ idxO,
                                                 float* __restrict__ out,
                                                 float* __restrict__ lossP,
                                                 int* __restrict__ counts) {
  int row = blockIdx.x, t = threadIdx.x;
  int idx = idxO[row];
  float4 e = ((const float4*)(E + (size_t)idx * DDIM))[t];
  float4 x = ((const float4*)(X + (size_t)row * DDIM))[t];
  // out + Q_OFF is only 4B aligned -> scalar stores
  float* q = out + Q_OFF + (size_t)row * DDIM + t * 4;
  q[0] = e.x; q[1] = e.y; q[2] = e.z; q[3] = e.w;
  float dx = e.x - x.x, dy = e.y - x.y, dz = e.z - x.z, dw = e.w - x.w;
  float s = dx*dx + dy*dy + dz*dz + dw*dw;
  #pragma unroll
  for (int d = 1; d < 64; d <<= 1) s += __shfl_xor(s, d);
  __shared__ float ls[2];
  if ((t & 63) == 0) ls[t >> 6] = s;
  __syncthreads();
  if (t == 0) {
    lossP[row] = ls[0] + ls[1];
    atomicAdd(&counts[idx], 1);
  }
}

// ---------------- one-hot encodings (256MB write) ---------------------------
__global__ __launch_bounds__(256) void vq_enc(const int* __restrict__ idxO,
                                              float* __restrict__ out) {
  int row = blockIdx.x, t = threadIdx.x;
  int idx = idxO[row];
  int k0 = t * 8;
  // base offset ENC_OFF + row*2048 + k0 is always even -> 8B aligned
  float2* dst = (float2*)(out + ENC_OFF + (size_t)row * KCOD + k0);
  dst[0] = make_float2(idx == k0     ? 1.f : 0.f, idx == k0 + 1 ? 1.f : 0.f);
  dst[1] = make_float2(idx == k0 + 2 ? 1.f : 0.f, idx == k0 + 3 ? 1.f : 0.f);
  dst[2] = make_float2(idx == k0 + 4 ? 1.f : 0.f, idx == k0 + 5 ? 1.f : 0.f);
  dst[3] = make_float2(idx == k0 + 6 ? 1.f : 0.f, idx == k0 + 7 ? 1.f : 0.f);
}

// ---------------- finalize: loss scalar + perplexity ------------------------
__global__ __launch_bounds__(256) void vq_fin(const float* __restrict__ lossP,
                                              const int* __restrict__ counts,
                                              float* __restrict__ out) {
  int t = threadIdx.x;
  float sl = 0.f;
  for (int i = t; i < NTOK; i += 256) sl += lossP[i];
  float sp = 0.f;
  for (int k = t; k < KCOD; k += 256) {
    float p = (float)counts[k] * (1.0f / NTOK);
    sp += p * logf(p + 1e-10f);
  }
  #pragma unroll
  for (int d = 1; d < 64; d <<= 1) {
    sl += __shfl_xor(sl, d);
    sp += __shfl_xor(sp, d);
  }
  __shared__ float lsA[4], lsB[4];
  if ((t & 63) == 0) { lsA[t >> 6] = sl; lsB[t >> 6] = sp; }
  __syncthreads();
  if (t == 0) {
    float L = lsA[0] + lsA[1] + lsA[2] + lsA[3];
    float P = lsB[0] + lsB[1] + lsB[2] + lsB[3];
    out[0] = 0.25f * L * (1.0f / 16777216.0f);
    out[PERP_OFF] = expf(-P);
  }
}

extern "C" void kernel_launch(void* const* d_in, const int* in_sizes, int n_in,
                              void* d_out, int out_size, void* d_ws, size_t ws_size,
                              hipStream_t stream) {
  const float* X = (const float*)d_in[0];   // [32768,512] f32
  const float* E = (const float*)d_in[1];   // [2048,512]  f32
  float* out = (float*)d_out;
  char* w = (char*)d_ws;
  __bf16* Ebf   = (__bf16*)(w + WS_EBF);
  float*  se    = (float*)(w + WS_SE);
  float*  wval  = (float*)(w + WS_WVAL);
  int*    widx  = (int*)(w + WS_WIDX);
  int*    idxO  = (int*)(w + WS_IDX);
  int*    counts= (int*)(w + WS_CNT);
  float*  lossP = (float*)(w + WS_LOSS);

  vq_prep<<<KCOD, 64, 0, stream>>>(E, Ebf, se, counts);
  vq_gemm<<<dim3(NTOK / 128, KCOD / 128), 256, 0, stream>>>(X, Ebf, se, wval, widx);
  vq_reduce<<<NTOK / 4, 256, 0, stream>>>(wval, widx, idxO);
  vq_gather<<<NTOK, 128, 0, stream>>>(X, E, idxO, out, lossP, counts);
  vq_enc<<<NTOK, 256, 0, stream>>>(idxO, out);
  vq_fin<<<1, 256, 0, stream>>>(lossP, counts, out);
}